// Round 1
// 147.118 us; speedup vs baseline: 1.0052x; 1.0052x over previous
//
#include <hip/hip_runtime.h>

#define NBLOCKS 2048
#define NTHREADS 256
#define UNROLL 8
#define NUM_LEVELS 101

// Stage 1: weighted-SSE partial sums, one float per block, written with a
// plain store (no device-scope atomic -> no cross-XCD RMW serialization tail).
__global__ __launch_bounds__(NTHREADS) void wmse_partial(
    const float* __restrict__ x,
    const float* __restrict__ y,
    const float* __restrict__ wt,
    float* __restrict__ partial, int n)
{
    __shared__ float s_wt[NUM_LEVELS];
    __shared__ float s_red[NTHREADS / 64];

    for (int i = threadIdx.x; i < NUM_LEVELS; i += NTHREADS) s_wt[i] = wt[i];
    __syncthreads();

    const float4* __restrict__ x4 = (const float4*)x;
    const float4* __restrict__ y4 = (const float4*)y;
    const int n4 = n >> 2;                 // N = 2^24, divisible by 4
    const int stride = NBLOCKS * NTHREADS; // 524288
    const int base = blockIdx.x * NTHREADS + threadIdx.x;

    float acc = 0.f;

    // Fast path: exactly UNROLL strided iterations (n4 == UNROLL*stride).
    if (n4 == UNROLL * stride) {
        float4 xs[UNROLL], ys[UNROLL];
        // Issue all 16 independent loads before any use -> deep vmcnt pipeline.
        #pragma unroll
        for (int k = 0; k < UNROLL; ++k) {
            xs[k] = x4[base + k * stride];
            ys[k] = y4[base + k * stride];
        }
        float a0 = 0.f, a1 = 0.f;
        #pragma unroll
        for (int k = 0; k < UNROLL; ++k) {
            float4 xv = xs[k], yv = ys[k];
            float w0 = s_wt[__float2int_rn(yv.x * 100.f)];
            float w1 = s_wt[__float2int_rn(yv.y * 100.f)];
            float w2 = s_wt[__float2int_rn(yv.z * 100.f)];
            float w3 = s_wt[__float2int_rn(yv.w * 100.f)];
            float d0 = xv.x - yv.x, d1 = xv.y - yv.y;
            float d2 = xv.z - yv.z, d3 = xv.w - yv.w;
            a0 += d0 * d0 * w0 + d2 * d2 * w2;
            a1 += d1 * d1 * w1 + d3 * d3 * w3;
        }
        acc = a0 + a1;
    } else {
        for (int i = base; i < n4; i += stride) {
            float4 xv = x4[i], yv = y4[i];
            float w0 = s_wt[__float2int_rn(yv.x * 100.f)];
            float w1 = s_wt[__float2int_rn(yv.y * 100.f)];
            float w2 = s_wt[__float2int_rn(yv.z * 100.f)];
            float w3 = s_wt[__float2int_rn(yv.w * 100.f)];
            float d0 = xv.x - yv.x, d1 = xv.y - yv.y;
            float d2 = xv.z - yv.z, d3 = xv.w - yv.w;
            acc += d0 * d0 * w0 + d1 * d1 * w1 + d2 * d2 * w2 + d3 * d3 * w3;
        }
    }

    // wave-64 shuffle reduction
    #pragma unroll
    for (int off = 32; off > 0; off >>= 1)
        acc += __shfl_down(acc, off, 64);

    const int lane = threadIdx.x & 63;
    const int wave = threadIdx.x >> 6;
    if (lane == 0) s_red[wave] = acc;
    __syncthreads();
    if (threadIdx.x == 0) {
        float s = 0.f;
        #pragma unroll
        for (int w = 0; w < NTHREADS / 64; ++w) s += s_red[w];
        partial[blockIdx.x] = s;   // plain store, no atomic
    }
}

// Stage 2: one block folds the 2048 partials and writes the final mean.
// Overwrites the poisoned output directly -> no memset node needed.
__global__ __launch_bounds__(NTHREADS) void wmse_reduce(
    const float* __restrict__ partial, float* __restrict__ out, float inv_n)
{
    __shared__ float s_red[NTHREADS / 64];
    float acc = 0.f;
    #pragma unroll
    for (int k = 0; k < NBLOCKS / NTHREADS; ++k)
        acc += partial[threadIdx.x + k * NTHREADS];

    #pragma unroll
    for (int off = 32; off > 0; off >>= 1)
        acc += __shfl_down(acc, off, 64);

    const int lane = threadIdx.x & 63;
    const int wave = threadIdx.x >> 6;
    if (lane == 0) s_red[wave] = acc;
    __syncthreads();
    if (threadIdx.x == 0) {
        float s = 0.f;
        #pragma unroll
        for (int w = 0; w < NTHREADS / 64; ++w) s += s_red[w];
        *out = s * inv_n;
    }
}

// Fallback (workspace too small): original atomic version.
__global__ __launch_bounds__(NTHREADS) void wmse_fused_atomic(
    const float* __restrict__ x,
    const float* __restrict__ y,
    const float* __restrict__ wt,
    float* __restrict__ out, int n, float inv_n)
{
    __shared__ float s_wt[NUM_LEVELS];
    __shared__ float s_red[NTHREADS / 64];

    for (int i = threadIdx.x; i < NUM_LEVELS; i += NTHREADS) s_wt[i] = wt[i];
    __syncthreads();

    const float4* __restrict__ x4 = (const float4*)x;
    const float4* __restrict__ y4 = (const float4*)y;
    const int n4 = n >> 2;
    const int stride = NBLOCKS * NTHREADS;
    const int base = blockIdx.x * NTHREADS + threadIdx.x;

    float acc = 0.f;
    for (int i = base; i < n4; i += stride) {
        float4 xv = x4[i], yv = y4[i];
        float w0 = s_wt[__float2int_rn(yv.x * 100.f)];
        float w1 = s_wt[__float2int_rn(yv.y * 100.f)];
        float w2 = s_wt[__float2int_rn(yv.z * 100.f)];
        float w3 = s_wt[__float2int_rn(yv.w * 100.f)];
        float d0 = xv.x - yv.x, d1 = xv.y - yv.y;
        float d2 = xv.z - yv.z, d3 = xv.w - yv.w;
        acc += d0 * d0 * w0 + d1 * d1 * w1 + d2 * d2 * w2 + d3 * d3 * w3;
    }

    #pragma unroll
    for (int off = 32; off > 0; off >>= 1)
        acc += __shfl_down(acc, off, 64);

    const int lane = threadIdx.x & 63;
    const int wave = threadIdx.x >> 6;
    if (lane == 0) s_red[wave] = acc;
    __syncthreads();
    if (threadIdx.x == 0) {
        float s = 0.f;
        #pragma unroll
        for (int w = 0; w < NTHREADS / 64; ++w) s += s_red[w];
        atomicAdd(out, s * inv_n);
    }
}

extern "C" void kernel_launch(void* const* d_in, const int* in_sizes, int n_in,
                              void* d_out, int out_size, void* d_ws, size_t ws_size,
                              hipStream_t stream) {
    const float* x  = (const float*)d_in[0];
    const float* y  = (const float*)d_in[1];
    const float* wt = (const float*)d_in[2];
    float* out = (float*)d_out;
    const int n = in_sizes[0];
    const float inv_n = 1.0f / (float)n;

    if (d_ws && ws_size >= NBLOCKS * sizeof(float)) {
        float* partial = (float*)d_ws;
        wmse_partial<<<NBLOCKS, NTHREADS, 0, stream>>>(x, y, wt, partial, n);
        wmse_reduce<<<1, NTHREADS, 0, stream>>>(partial, out, inv_n);
    } else {
        hipMemsetAsync(out, 0, sizeof(float), stream);
        wmse_fused_atomic<<<NBLOCKS, NTHREADS, 0, stream>>>(x, y, wt, out, n, inv_n);
    }
}